// Round 9
// baseline (165.501 us; speedup 1.0000x reference)
//
#include <hip/hip_runtime.h>

#define DEG 32
#define SAW 232   // sA row stride in halves (464 B: 16B-aligned, 2-way-bank-free)
#define NT  4     // 64-edge tiles per block; grid = 262144/(64*NT) = 1024

typedef _Float16 half8 __attribute__((ext_vector_type(8)));
typedef __fp16 fp16x2 __attribute__((ext_vector_type(2)));
typedef float f32x4 __attribute__((ext_vector_type(4)));
typedef int int4v __attribute__((ext_vector_type(4)));

#define EXP2F(x)   __builtin_amdgcn_exp2f(x)
#define SIN_REV(x) __builtin_amdgcn_sinf(x)   // sin(2*pi*x)
#define COS_REV(x) __builtin_amdgcn_cosf(x)   // cos(2*pi*x)
#define RCPF(x)    __builtin_amdgcn_rcpf(x)
#define INV_2PI    0.15915494309189535f
#define NEG_L2_10K_O32 -0.41524101186092046f  // -log2(10000)/32

// 7-inst tanh-GELU: x - x/(1+e^{2z}), with 2z*log2e = x*(c1 + c2*x^2)
__device__ __forceinline__ float gelu_f(float x){
  float x2 = x * x;
  float t  = __builtin_fmaf(0.10294824f, x2, 2.3022079f);
  float e  = EXP2F(x * t);
  float r  = RCPF(1.0f + e);
  return __builtin_fmaf(-x, r, x);
}

__device__ __forceinline__ int pkh(float a, float b){
  fp16x2 p = __builtin_amdgcn_cvt_pkrtz(a, b);
  return __builtin_bit_cast(int, p);
}

__device__ __forceinline__ float wave_reduce(float v){
  #pragma unroll
  for (int s = 1; s < 64; s <<= 1) v += __shfl_xor(v, s, 64);
  return v;
}

// trig fill for ROWS rows (8 or 64): t<192, 3 waves (w=axis) x (g=freq-blk, r16)
template<int ROWS>
__device__ __forceinline__ void tile_trig(_Float16 (*sA)[SAW], const float (*sPos)[3],
    const float* sOmg, int t){
  if (t < 192){
    int lane = t & 63, w = t >> 6;
    int r16 = lane & 15, g = lane >> 4;
    if (ROWS < 16 && r16 >= ROWS) return;
    float om[8];
    #pragma unroll
    for (int j = 0; j < 8; j++) om[j] = sOmg[8*g + j];
    constexpr int NRR = (ROWS >= 16) ? ROWS/16 : 1;
    #pragma unroll
    for (int rr = 0; rr < NRR; rr++){
      int row = r16 + rr*16;
      float p = sPos[row][w];
      float a[8];
      #pragma unroll
      for (int j = 0; j < 8; j++) a[j] = p * om[j];
      int4v sv, cv;
      #pragma unroll
      for (int j = 0; j < 4; j++){
        sv[j] = pkh(SIN_REV(a[2*j]), SIN_REV(a[2*j+1]));
        cv[j] = pkh(COS_REV(a[2*j]), COS_REV(a[2*j+1]));
      }
      int ch = w*8 + g;                     // sin chunk; cos at ch+4
      *reinterpret_cast<int4v*>(&sA[row][8*ch])     = sv;
      *reinterpret_cast<int4v*>(&sA[row][8*(ch+4)]) = cv;
    }
  }
}

// ---- K0: folded-weight prep (wave-parallel) ----
__global__ void k0_prep(const float* __restrict__ W_in, const float* __restrict__ b_in,
    const float* __restrict__ W1, const float* __restrict__ b1,
    const float* __restrict__ W2,
    _Float16* __restrict__ w1tc, _Float16* __restrict__ w1bc,
    _Float16* __restrict__ w2t, float* __restrict__ bias_c){
  int id = blockIdx.x * 256 + threadIdx.x;
  if (id < 86016){
    int half_sel = id / 43008;
    int i = id - half_sel * 43008;
    int n = i / 224, k = i - n * 224;
    const float* Wh = W1 + half_sel * 192 * 192;
    _Float16* dst = half_sel ? w1bc : w1tc;
    if (k < 192)      dst[i] = (_Float16)Wh[k*192 + n];
    else if (k >= 195) dst[i] = (_Float16)0.f;
  } else if (id < 122880){
    int i = id - 86016;
    int n = i / 192, k = i - n * 192;
    w2t[i] = (_Float16)(W2[k*192 + n] * 0.03125f);
  } else if (id < 135168){
    int o = (id - 122880) >> 6, lane = id & 63;
    float s = 0.f;
    #pragma unroll
    for (int u = 0; u < 3; u++){
      int m = lane + 64*u;
      s += b_in[m] * (W1[m*192 + o] + W1[(m+192)*192 + o]);
    }
    s = wave_reduce(s);
    if (lane == 0) bias_c[o] = s + b1[o];
  } else if (id < 208896){
    int o = (id - 135168) >> 6, lane = id & 63;
    int half_sel = o / 576;
    int rem = o - half_sel * 576;
    int r = rem / 192, n = rem - r * 192;
    const float* Wh = W1 + half_sel * 192 * 192;
    float s = 0.f;
    #pragma unroll
    for (int u = 0; u < 3; u++){
      int m = lane + 64*u;
      s += W_in[r*192 + m] * Wh[m*192 + n];
    }
    s = wave_reduce(s);
    if (lane == 0){
      _Float16* dst = half_sel ? w1bc : w1tc;
      dst[n*224 + 192 + r] = (_Float16)s;
    }
  }
}

// ---- K2: fused dst-prologue + pipelined 4-tile edge kernel ----
__global__ __launch_bounds__(256, 4) void k2_fused(const int* __restrict__ src_idx,
    const int* __restrict__ dst_idx,
    const float* __restrict__ feat, const float* __restrict__ pos,
    const _Float16* __restrict__ w1tc, const _Float16* __restrict__ w1bc,
    const float* __restrict__ bias_c, _Float16* __restrict__ S1){
  __shared__ _Float16 sA[64][SAW];          // 29.7 KB, single-buffered
  __shared__ _Float16 sAd[2*NT][192];       // 3 KB: per-supernode dst activations
  __shared__ float sPos[2][64][3];          // 1.5 KB, double-buffered
  __shared__ float sOmg[32];
  int blk = blockIdx.x, t = threadIdx.x;
  int wave = t >> 6, lane = t & 63, ln15 = lane & 15, grp = lane >> 4;
  int e0 = blk * (NT*64);
  int s0 = blk * (NT*2);

  if (t < 32) sOmg[t] = EXP2F((float)t * NEG_L2_10K_O32) * INV_2PI;
  // persistent zero pad: cols 200..223, all rows (written once, never touched again)
  if (t < 64){
    int4v z; z[0] = 0; z[1] = 0; z[2] = 0; z[3] = 0;
    *reinterpret_cast<int4v*>(&sA[t][200]) = z;
    *reinterpret_cast<int4v*>(&sA[t][208]) = z;
    *reinterpret_cast<int4v*>(&sA[t][216]) = z;
  }
  // src_idx preload: gathering threads hold their NT indices in regs
  int idxA[NT];
  if (t < 64){
    #pragma unroll
    for (int tl = 0; tl < NT; tl++) idxA[tl] = src_idx[e0 + tl*64 + t];
  } else if (t >= 192){
    #pragma unroll
    for (int tl = 0; tl < NT; tl++) idxA[tl] = src_idx[e0 + tl*64 + (t-192)];
  }
  // dst gather (8 supernodes): pos -> sPos[1] rows 0..7, feat -> sA rows 0..7
  if (t < 8){
    int nd = dst_idx[(s0 + t) * DEG];
    sPos[1][t][0] = pos[3*nd]; sPos[1][t][1] = pos[3*nd+1]; sPos[1][t][2] = pos[3*nd+2];
  } else if (t >= 192 && t < 200){
    int e = t - 192;
    int nd = dst_idx[(s0 + e) * DEG];
    float f0 = feat[3*nd], f1 = feat[3*nd+1], f2 = feat[3*nd+2];
    int4v v0; v0[0] = pkh(f0, f1); v0[1] = pkh(f2, 0.f); v0[2] = 0; v0[3] = 0;
    *reinterpret_cast<int4v*>(&sA[e][192]) = v0;
  }
  __syncthreads();
  tile_trig<8>(sA, sPos[1], sOmg, t);
  // tile-0 gather into regs (latency hides under dst trig+GEMM)
  float p0 = 0.f, p1 = 0.f, p2 = 0.f;
  if (t < 64){
    int nd = idxA[0];
    p0 = pos[3*nd]; p1 = pos[3*nd+1]; p2 = pos[3*nd+2];
  } else if (t >= 192){
    int nd = idxA[0];
    p0 = feat[3*nd]; p1 = feat[3*nd+1]; p2 = feat[3*nd+2];
  }
  __syncthreads();
  // dst GEMM: M=16 tile (rows 8..15 garbage, discarded); B = w1bc streamed
  {
    f32x4 a1[3];
    #pragma unroll
    for (int n = 0; n < 3; n++) a1[n] = (f32x4){0.f, 0.f, 0.f, 0.f};
    #pragma unroll
    for (int k6 = 0; k6 < 7; k6++){
      half8 Af = *reinterpret_cast<const half8*>(&sA[ln15][k6*32 + grp*8]);
      #pragma unroll
      for (int n = 0; n < 3; n++){
        half8 Bf = *reinterpret_cast<const half8*>(w1bc + (wave*48 + n*16 + ln15)*224 + k6*32 + grp*8);
        a1[n] = __builtin_amdgcn_mfma_f32_16x16x32_f16(Af, Bf, a1[n], 0, 0, 0);
      }
    }
    #pragma unroll
    for (int n = 0; n < 3; n++){
      int col = wave*48 + n*16 + ln15;
      float bc = bias_c[col];
      #pragma unroll
      for (int r = 0; r < 4; r++){
        int row = grp*4 + r;
        if (row < 8) sAd[row][col] = (_Float16)(a1[n][r] + bc);
      }
    }
  }
  __syncthreads();
  // write tile 0 into sA/sPos[0]
  if (t < 64){
    sPos[0][t][0] = p0; sPos[0][t][1] = p1; sPos[0][t][2] = p2;
  } else if (t >= 192){
    int4v v0; v0[0] = pkh(p0, p1); v0[1] = pkh(p2, 0.f); v0[2] = 0; v0[3] = 0;
    *reinterpret_cast<int4v*>(&sA[t-192][192]) = v0;
  }
  __syncthreads();

  for (int tl = 0; tl < NT; ++tl){
    // 1) issue gather for tile tl+1 (regs; consumed after bar2)
    if (tl + 1 < NT){
      if (t < 64){
        int nd = idxA[tl+1];
        p0 = pos[3*nd]; p1 = pos[3*nd+1]; p2 = pos[3*nd+2];
      } else if (t >= 192){
        int nd = idxA[tl+1];
        p0 = feat[3*nd]; p1 = feat[3*nd+1]; p2 = feat[3*nd+2];
      }
    }
    // 2) dst activations for this tile (LDS, stable since prologue)
    float ad[2][3];
    #pragma unroll
    for (int h = 0; h < 2; h++)
      #pragma unroll
      for (int n = 0; n < 3; n++)
        ad[h][n] = (float)sAd[tl*2 + h][wave*48 + n*16 + ln15];
    // 3) trig fill current tile
    tile_trig<64>(sA, sPos[tl & 1], sOmg, t);
    __syncthreads();
    // 4) MFMA, B streamed from w1tc (L1/L2-resident)
    f32x4 acc[4][3];
    #pragma unroll
    for (int m = 0; m < 4; m++)
      #pragma unroll
      for (int n = 0; n < 3; n++) acc[m][n] = (f32x4){0.f, 0.f, 0.f, 0.f};
    #pragma unroll
    for (int k6 = 0; k6 < 7; k6++){
      half8 Af[4];
      #pragma unroll
      for (int m = 0; m < 4; m++)
        Af[m] = *reinterpret_cast<const half8*>(&sA[m*16 + ln15][k6*32 + grp*8]);
      #pragma unroll
      for (int n = 0; n < 3; n++){
        half8 Bf = *reinterpret_cast<const half8*>(w1tc + (wave*48 + n*16 + ln15)*224 + k6*32 + grp*8);
        #pragma unroll
        for (int m = 0; m < 4; m++)
          acc[m][n] = __builtin_amdgcn_mfma_f32_16x16x32_f16(Af[m], Bf, acc[m][n], 0, 0, 0);
      }
    }
    // 5) epilogue: gelu + row-sum per supernode half
    #pragma unroll
    for (int h = 0; h < 2; h++){
      #pragma unroll
      for (int n = 0; n < 3; n++){
        float cs = 0.f;
        #pragma unroll
        for (int mm = 0; mm < 2; mm++){
          f32x4 a = acc[h*2 + mm][n];
          #pragma unroll
          for (int r = 0; r < 4; r++) cs += gelu_f(a[r] + ad[h][n]);
        }
        cs += __shfl_xor(cs, 16, 64);
        cs += __shfl_xor(cs, 32, 64);
        if (grp == 0)
          S1[(s0 + tl*2 + h)*192 + wave*48 + n*16 + ln15] = (_Float16)cs;
      }
    }
    // 6) pos for tile tl+1 -> other sPos buffer (before bar; next trig reads it)
    if (tl + 1 < NT && t < 64){
      int nxt = (tl+1) & 1;
      sPos[nxt][t][0] = p0; sPos[nxt][t][1] = p1; sPos[nxt][t][2] = p2;
    }
    __syncthreads();
    // 7) feat write into sA (disjoint cols vs next trig; read after next bar)
    if (tl + 1 < NT && t >= 192){
      int4v v0; v0[0] = pkh(p0, p1); v0[1] = pkh(p2, 0.f); v0[2] = 0; v0[3] = 0;
      *reinterpret_cast<int4v*>(&sA[t-192][192]) = v0;
    }
  }
}

// ---- K3: out[8192][192] = S1 @ (W2/32) + b2 ----
__global__ __launch_bounds__(256) void k3_out(const _Float16* __restrict__ S1,
    const _Float16* __restrict__ w2t, const float* __restrict__ b2,
    float* __restrict__ out){
  int blk = blockIdx.x, t = threadIdx.x;
  int wave = t >> 6, lane = t & 63, ln15 = lane & 15, grp = lane >> 4;
  f32x4 acc[4][3];
  #pragma unroll
  for (int m = 0; m < 4; m++)
    #pragma unroll
    for (int n = 0; n < 3; n++) acc[m][n] = (f32x4){0.f, 0.f, 0.f, 0.f};
  #pragma unroll
  for (int k6 = 0; k6 < 6; k6++){
    half8 Af[4];
    #pragma unroll
    for (int m = 0; m < 4; m++)
      Af[m] = *reinterpret_cast<const half8*>(S1 + (blk*64 + m*16 + ln15)*192 + k6*32 + grp*8);
    #pragma unroll
    for (int n = 0; n < 3; n++){
      half8 Bf = *reinterpret_cast<const half8*>(w2t + (wave*48 + n*16 + ln15)*192 + k6*32 + grp*8);
      #pragma unroll
      for (int m = 0; m < 4; m++)
        acc[m][n] = __builtin_amdgcn_mfma_f32_16x16x32_f16(Af[m], Bf, acc[m][n], 0, 0, 0);
    }
  }
  #pragma unroll
  for (int n = 0; n < 3; n++){
    int col = wave*48 + n*16 + ln15;
    float bias = b2[col];
    #pragma unroll
    for (int m = 0; m < 4; m++)
      #pragma unroll
      for (int r = 0; r < 4; r++)
        out[(blk*64 + m*16 + grp*4 + r)*192 + col] = acc[m][n][r] + bias;
  }
}

extern "C" void kernel_launch(void* const* d_in, const int* in_sizes, int n_in,
                              void* d_out, int out_size, void* d_ws, size_t ws_size,
                              hipStream_t stream) {
  const float* feat   = (const float*)d_in[0];
  const float* pos    = (const float*)d_in[1];
  const int*   src_i  = (const int*)  d_in[2];
  const int*   dst_i  = (const int*)  d_in[3];
  const float* W_in   = (const float*)d_in[4];
  const float* b_in   = (const float*)d_in[5];
  const float* W1     = (const float*)d_in[6];
  const float* b1     = (const float*)d_in[7];
  const float* W2     = (const float*)d_in[8];
  const float* b2     = (const float*)d_in[9];
  float* out = (float*)d_out;

  char* ws = (char*)d_ws;
  _Float16* w1tc   = (_Float16*)(ws);                 // 192*224*2 =  86016 B
  _Float16* w1bc   = (_Float16*)(ws + 86016);         //              86016 B
  _Float16* w2t    = (_Float16*)(ws + 172032);        // 192*192*2 =  73728 B
  float*    bias_c = (float*)   (ws + 245760);        //                768 B
  _Float16* S1     = (_Float16*)(ws + 246528);        // 8192*192*2 = 3145728 B
  // total ws use: 3392256 B

  k0_prep <<<816, 256, 0, stream>>>(W_in, b_in, W1, b1, W2, w1tc, w1bc, w2t, bias_c);
  k2_fused<<<1024, 256, 0, stream>>>(src_i, dst_i, feat, pos, w1tc, w1bc, bias_c, S1);
  k3_out  <<<128, 256, 0, stream>>>(S1, w2t, b2, out);
}

// Round 10
// 134.307 us; speedup vs baseline: 1.2323x; 1.2323x over previous
//
#include <hip/hip_runtime.h>

#define DEG 32
#define SAW 232   // sA row stride in halves (464 B: 16B-aligned, 2-way-bank-free)
#define NT  4     // 64-edge tiles per block; grid = 262144/(64*NT) = 1024

typedef _Float16 half8 __attribute__((ext_vector_type(8)));
typedef __fp16 fp16x2 __attribute__((ext_vector_type(2)));
typedef float f32x4 __attribute__((ext_vector_type(4)));
typedef int int4v __attribute__((ext_vector_type(4)));

#define EXP2F(x)   __builtin_amdgcn_exp2f(x)
#define SIN_REV(x) __builtin_amdgcn_sinf(x)   // sin(2*pi*x)
#define COS_REV(x) __builtin_amdgcn_cosf(x)   // cos(2*pi*x)
#define RCPF(x)    __builtin_amdgcn_rcpf(x)
#define INV_2PI    0.15915494309189535f
#define NEG_L2_10K_O32 -0.41524101186092046f  // -log2(10000)/32

// 7-inst tanh-GELU: x - x/(1+e^{2z}), with 2z*log2e = x*(c1 + c2*x^2)
__device__ __forceinline__ float gelu_f(float x){
  float x2 = x * x;
  float t  = __builtin_fmaf(0.10294824f, x2, 2.3022079f);
  float e  = EXP2F(x * t);
  float r  = RCPF(1.0f + e);
  return __builtin_fmaf(-x, r, x);
}

__device__ __forceinline__ int pkh(float a, float b){
  fp16x2 p = __builtin_amdgcn_cvt_pkrtz(a, b);
  return __builtin_bit_cast(int, p);
}

__device__ __forceinline__ float wave_reduce(float v){
  #pragma unroll
  for (int s = 1; s < 64; s <<= 1) v += __shfl_xor(v, s, 64);
  return v;
}

// trig fill for ROWS rows (8 or 64): t<192, 3 waves (w=axis) x (g=freq-blk, r16)
template<int ROWS>
__device__ __forceinline__ void tile_trig(_Float16 (*sA)[SAW], const float (*sPos)[3],
    const float* sOmg, int t){
  if (t < 192){
    int lane = t & 63, w = t >> 6;
    int r16 = lane & 15, g = lane >> 4;
    if (ROWS < 16 && r16 >= ROWS) return;
    float om[8];
    #pragma unroll
    for (int j = 0; j < 8; j++) om[j] = sOmg[8*g + j];
    constexpr int NRR = (ROWS >= 16) ? ROWS/16 : 1;
    #pragma unroll
    for (int rr = 0; rr < NRR; rr++){
      int row = r16 + rr*16;
      float p = sPos[row][w];
      float a[8];
      #pragma unroll
      for (int j = 0; j < 8; j++) a[j] = p * om[j];
      int4v sv, cv;
      #pragma unroll
      for (int j = 0; j < 4; j++){
        sv[j] = pkh(SIN_REV(a[2*j]), SIN_REV(a[2*j+1]));
        cv[j] = pkh(COS_REV(a[2*j]), COS_REV(a[2*j+1]));
      }
      int ch = w*8 + g;                     // sin chunk; cos at ch+4
      *reinterpret_cast<int4v*>(&sA[row][8*ch])     = sv;
      *reinterpret_cast<int4v*>(&sA[row][8*(ch+4)]) = cv;
    }
  }
}

// ---- K0: folded-weight prep (wave-parallel) ----
__global__ void k0_prep(const float* __restrict__ W_in, const float* __restrict__ b_in,
    const float* __restrict__ W1, const float* __restrict__ b1,
    const float* __restrict__ W2,
    _Float16* __restrict__ w1tc, _Float16* __restrict__ w1bc,
    _Float16* __restrict__ w2t, float* __restrict__ bias_c){
  int id = blockIdx.x * 256 + threadIdx.x;
  if (id < 86016){
    int half_sel = id / 43008;
    int i = id - half_sel * 43008;
    int n = i / 224, k = i - n * 224;
    const float* Wh = W1 + half_sel * 192 * 192;
    _Float16* dst = half_sel ? w1bc : w1tc;
    if (k < 192)      dst[i] = (_Float16)Wh[k*192 + n];
    else if (k >= 195) dst[i] = (_Float16)0.f;
  } else if (id < 122880){
    int i = id - 86016;
    int n = i / 192, k = i - n * 192;
    w2t[i] = (_Float16)(W2[k*192 + n] * 0.03125f);
  } else if (id < 135168){
    int o = (id - 122880) >> 6, lane = id & 63;
    float s = 0.f;
    #pragma unroll
    for (int u = 0; u < 3; u++){
      int m = lane + 64*u;
      s += b_in[m] * (W1[m*192 + o] + W1[(m+192)*192 + o]);
    }
    s = wave_reduce(s);
    if (lane == 0) bias_c[o] = s + b1[o];
  } else if (id < 208896){
    int o = (id - 135168) >> 6, lane = id & 63;
    int half_sel = o / 576;
    int rem = o - half_sel * 576;
    int r = rem / 192, n = rem - r * 192;
    const float* Wh = W1 + half_sel * 192 * 192;
    float s = 0.f;
    #pragma unroll
    for (int u = 0; u < 3; u++){
      int m = lane + 64*u;
      s += W_in[r*192 + m] * Wh[m*192 + n];
    }
    s = wave_reduce(s);
    if (lane == 0){
      _Float16* dst = half_sel ? w1bc : w1tc;
      dst[n*224 + 192 + r] = (_Float16)s;
    }
  }
}

// ---- K2: fused dst-prologue + pipelined 4-tile edge kernel ----
__global__ __launch_bounds__(256) void k2_fused(const int* __restrict__ src_idx,
    const int* __restrict__ dst_idx,
    const float* __restrict__ feat, const float* __restrict__ pos,
    const _Float16* __restrict__ w1tc, const _Float16* __restrict__ w1bc,
    const float* __restrict__ bias_c, _Float16* __restrict__ S1){
  __shared__ _Float16 sA[64][SAW];          // 29.7 KB, single-buffered
  __shared__ _Float16 sAd[2*NT][192];       // 3 KB: per-supernode dst activations
  __shared__ float sPos[2][64][3];          // 1.5 KB, double-buffered
  __shared__ float sOmg[32];
  int blk = blockIdx.x, t = threadIdx.x;
  int wave = t >> 6, lane = t & 63, ln15 = lane & 15, grp = lane >> 4;
  int e0 = blk * (NT*64);
  int s0 = blk * (NT*2);

  if (t < 32) sOmg[t] = EXP2F((float)t * NEG_L2_10K_O32) * INV_2PI;
  // persistent zero pad: cols 200..223, all rows (written once, never touched again)
  if (t < 64){
    int4v z; z[0] = 0; z[1] = 0; z[2] = 0; z[3] = 0;
    *reinterpret_cast<int4v*>(&sA[t][200]) = z;
    *reinterpret_cast<int4v*>(&sA[t][208]) = z;
    *reinterpret_cast<int4v*>(&sA[t][216]) = z;
  }
  // src_idx preload: gathering threads hold their NT indices in regs
  int idxA[NT];
  if (t < 64){
    #pragma unroll
    for (int tl = 0; tl < NT; tl++) idxA[tl] = src_idx[e0 + tl*64 + t];
  } else if (t >= 192){
    #pragma unroll
    for (int tl = 0; tl < NT; tl++) idxA[tl] = src_idx[e0 + tl*64 + (t-192)];
  }
  // dst gather (8 supernodes): pos -> sPos[1] rows 0..7, feat -> sA rows 0..7
  if (t < 8){
    int nd = dst_idx[(s0 + t) * DEG];
    sPos[1][t][0] = pos[3*nd]; sPos[1][t][1] = pos[3*nd+1]; sPos[1][t][2] = pos[3*nd+2];
  } else if (t >= 192 && t < 200){
    int e = t - 192;
    int nd = dst_idx[(s0 + e) * DEG];
    float f0 = feat[3*nd], f1 = feat[3*nd+1], f2 = feat[3*nd+2];
    int4v v0; v0[0] = pkh(f0, f1); v0[1] = pkh(f2, 0.f); v0[2] = 0; v0[3] = 0;
    *reinterpret_cast<int4v*>(&sA[e][192]) = v0;
  }
  __syncthreads();
  tile_trig<8>(sA, sPos[1], sOmg, t);
  // tile-0 gather into regs (latency hides under dst trig+GEMM)
  float p0 = 0.f, p1 = 0.f, p2 = 0.f;
  if (t < 64){
    int nd = idxA[0];
    p0 = pos[3*nd]; p1 = pos[3*nd+1]; p2 = pos[3*nd+2];
  } else if (t >= 192){
    int nd = idxA[0];
    p0 = feat[3*nd]; p1 = feat[3*nd+1]; p2 = feat[3*nd+2];
  }
  __syncthreads();
  // dst GEMM: M=16 tile (rows 8..15 garbage, discarded); B = w1bc streamed
  {
    f32x4 a1[3];
    #pragma unroll
    for (int n = 0; n < 3; n++) a1[n] = (f32x4){0.f, 0.f, 0.f, 0.f};
    #pragma unroll
    for (int k6 = 0; k6 < 7; k6++){
      half8 Af = *reinterpret_cast<const half8*>(&sA[ln15][k6*32 + grp*8]);
      #pragma unroll
      for (int n = 0; n < 3; n++){
        half8 Bf = *reinterpret_cast<const half8*>(w1bc + (wave*48 + n*16 + ln15)*224 + k6*32 + grp*8);
        a1[n] = __builtin_amdgcn_mfma_f32_16x16x32_f16(Af, Bf, a1[n], 0, 0, 0);
      }
    }
    #pragma unroll
    for (int n = 0; n < 3; n++){
      int col = wave*48 + n*16 + ln15;
      float bc = bias_c[col];
      #pragma unroll
      for (int r = 0; r < 4; r++){
        int row = grp*4 + r;
        if (row < 8) sAd[row][col] = (_Float16)(a1[n][r] + bc);
      }
    }
  }
  __syncthreads();
  // write tile 0 into sA/sPos[0]
  if (t < 64){
    sPos[0][t][0] = p0; sPos[0][t][1] = p1; sPos[0][t][2] = p2;
  } else if (t >= 192){
    int4v v0; v0[0] = pkh(p0, p1); v0[1] = pkh(p2, 0.f); v0[2] = 0; v0[3] = 0;
    *reinterpret_cast<int4v*>(&sA[t-192][192]) = v0;
  }
  __syncthreads();

  for (int tl = 0; tl < NT; ++tl){
    // 1) issue gather for tile tl+1 (regs; consumed after bar2)
    if (tl + 1 < NT){
      if (t < 64){
        int nd = idxA[tl+1];
        p0 = pos[3*nd]; p1 = pos[3*nd+1]; p2 = pos[3*nd+2];
      } else if (t >= 192){
        int nd = idxA[tl+1];
        p0 = feat[3*nd]; p1 = feat[3*nd+1]; p2 = feat[3*nd+2];
      }
    }
    // 2) dst activations for this tile (LDS, stable since prologue)
    float ad[2][3];
    #pragma unroll
    for (int h = 0; h < 2; h++)
      #pragma unroll
      for (int n = 0; n < 3; n++)
        ad[h][n] = (float)sAd[tl*2 + h][wave*48 + n*16 + ln15];
    // 3) trig fill current tile
    tile_trig<64>(sA, sPos[tl & 1], sOmg, t);
    __syncthreads();
    // 4) MFMA, B streamed from w1tc (L1/L2-resident)
    f32x4 acc[4][3];
    #pragma unroll
    for (int m = 0; m < 4; m++)
      #pragma unroll
      for (int n = 0; n < 3; n++) acc[m][n] = (f32x4){0.f, 0.f, 0.f, 0.f};
    #pragma unroll
    for (int k6 = 0; k6 < 7; k6++){
      half8 Af[4];
      #pragma unroll
      for (int m = 0; m < 4; m++)
        Af[m] = *reinterpret_cast<const half8*>(&sA[m*16 + ln15][k6*32 + grp*8]);
      #pragma unroll
      for (int n = 0; n < 3; n++){
        half8 Bf = *reinterpret_cast<const half8*>(w1tc + (wave*48 + n*16 + ln15)*224 + k6*32 + grp*8);
        #pragma unroll
        for (int m = 0; m < 4; m++)
          acc[m][n] = __builtin_amdgcn_mfma_f32_16x16x32_f16(Af[m], Bf, acc[m][n], 0, 0, 0);
      }
    }
    // 5) epilogue: gelu + row-sum per supernode half
    #pragma unroll
    for (int h = 0; h < 2; h++){
      #pragma unroll
      for (int n = 0; n < 3; n++){
        float cs = 0.f;
        #pragma unroll
        for (int mm = 0; mm < 2; mm++){
          f32x4 a = acc[h*2 + mm][n];
          #pragma unroll
          for (int r = 0; r < 4; r++) cs += gelu_f(a[r] + ad[h][n]);
        }
        cs += __shfl_xor(cs, 16, 64);
        cs += __shfl_xor(cs, 32, 64);
        if (grp == 0)
          S1[(s0 + tl*2 + h)*192 + wave*48 + n*16 + ln15] = (_Float16)cs;
      }
    }
    // 6) pos for tile tl+1 -> other sPos buffer (before bar; next trig reads it)
    if (tl + 1 < NT && t < 64){
      int nxt = (tl+1) & 1;
      sPos[nxt][t][0] = p0; sPos[nxt][t][1] = p1; sPos[nxt][t][2] = p2;
    }
    __syncthreads();
    // 7) feat write into sA (disjoint cols vs next trig; read after next bar)
    if (tl + 1 < NT && t >= 192){
      int4v v0; v0[0] = pkh(p0, p1); v0[1] = pkh(p2, 0.f); v0[2] = 0; v0[3] = 0;
      *reinterpret_cast<int4v*>(&sA[t-192][192]) = v0;
    }
  }
}

// ---- K3: out[8192][192] = S1 @ (W2/32) + b2 ----
__global__ __launch_bounds__(256) void k3_out(const _Float16* __restrict__ S1,
    const _Float16* __restrict__ w2t, const float* __restrict__ b2,
    float* __restrict__ out){
  int blk = blockIdx.x, t = threadIdx.x;
  int wave = t >> 6, lane = t & 63, ln15 = lane & 15, grp = lane >> 4;
  f32x4 acc[4][3];
  #pragma unroll
  for (int m = 0; m < 4; m++)
    #pragma unroll
    for (int n = 0; n < 3; n++) acc[m][n] = (f32x4){0.f, 0.f, 0.f, 0.f};
  #pragma unroll
  for (int k6 = 0; k6 < 6; k6++){
    half8 Af[4];
    #pragma unroll
    for (int m = 0; m < 4; m++)
      Af[m] = *reinterpret_cast<const half8*>(S1 + (blk*64 + m*16 + ln15)*192 + k6*32 + grp*8);
    #pragma unroll
    for (int n = 0; n < 3; n++){
      half8 Bf = *reinterpret_cast<const half8*>(w2t + (wave*48 + n*16 + ln15)*192 + k6*32 + grp*8);
      #pragma unroll
      for (int m = 0; m < 4; m++)
        acc[m][n] = __builtin_amdgcn_mfma_f32_16x16x32_f16(Af[m], Bf, acc[m][n], 0, 0, 0);
    }
  }
  #pragma unroll
  for (int n = 0; n < 3; n++){
    int col = wave*48 + n*16 + ln15;
    float bias = b2[col];
    #pragma unroll
    for (int m = 0; m < 4; m++)
      #pragma unroll
      for (int r = 0; r < 4; r++)
        out[(blk*64 + m*16 + grp*4 + r)*192 + col] = acc[m][n][r] + bias;
  }
}

extern "C" void kernel_launch(void* const* d_in, const int* in_sizes, int n_in,
                              void* d_out, int out_size, void* d_ws, size_t ws_size,
                              hipStream_t stream) {
  const float* feat   = (const float*)d_in[0];
  const float* pos    = (const float*)d_in[1];
  const int*   src_i  = (const int*)  d_in[2];
  const int*   dst_i  = (const int*)  d_in[3];
  const float* W_in   = (const float*)d_in[4];
  const float* b_in   = (const float*)d_in[5];
  const float* W1     = (const float*)d_in[6];
  const float* b1     = (const float*)d_in[7];
  const float* W2     = (const float*)d_in[8];
  const float* b2     = (const float*)d_in[9];
  float* out = (float*)d_out;

  char* ws = (char*)d_ws;
  _Float16* w1tc   = (_Float16*)(ws);                 // 192*224*2 =  86016 B
  _Float16* w1bc   = (_Float16*)(ws + 86016);         //              86016 B
  _Float16* w2t    = (_Float16*)(ws + 172032);        // 192*192*2 =  73728 B
  float*    bias_c = (float*)   (ws + 245760);        //                768 B
  _Float16* S1     = (_Float16*)(ws + 246528);        // 8192*192*2 = 3145728 B
  // total ws use: 3392256 B

  k0_prep <<<816, 256, 0, stream>>>(W_in, b_in, W1, b1, W2, w1tc, w1bc, w2t, bias_c);
  k2_fused<<<1024, 256, 0, stream>>>(src_i, dst_i, feat, pos, w1tc, w1bc, bias_c, S1);
  k3_out  <<<128, 256, 0, stream>>>(S1, w2t, b2, out);
}